// Round 1
// baseline (314.403 us; speedup 1.0000x reference)
//
#include <hip/hip_runtime.h>

// Problem constants (B, Q, K, D fixed by the reference).
constexpr int BATCH = 32;
constexpr int QLEN  = 1024;
constexpr int KLEN  = 1024;
constexpr int DIM   = 64;
constexpr int TQ    = 16;    // query rows per block
constexpr int SC_STRIDE = 1032; // f16 elems per score row (1024 + 8 pad; keeps 16B row align, odd bank-quad)
constexpr int VT_STRIDE = 136;  // f16 elems per Vt row (128 k + 8 pad)

typedef float    f32x4 __attribute__((ext_vector_type(4)));
typedef int      i32x4 __attribute__((ext_vector_type(4)));
typedef _Float16 f16x8 __attribute__((ext_vector_type(8)));
typedef _Float16 f16x4 __attribute__((ext_vector_type(4)));

__device__ __forceinline__ f16x8 cvt_h8(f32x4 a, f32x4 b) {
  f16x8 h;
  h[0] = (_Float16)a[0]; h[1] = (_Float16)a[1]; h[2] = (_Float16)a[2]; h[3] = (_Float16)a[3];
  h[4] = (_Float16)b[0]; h[5] = (_Float16)b[1]; h[6] = (_Float16)b[2]; h[7] = (_Float16)b[3];
  return h;
}

__global__ __launch_bounds__(256, 3)
void sdpa_kernel(const float* __restrict__ Qg, const float* __restrict__ Kg,
                 const float* __restrict__ Vg, const int* __restrict__ Mg,
                 float* __restrict__ Ctx, float* __restrict__ Attn)
{
  // 33,024 B scores/probs (f16) + 17,408 B V^T tile = 50,432 B -> 3 blocks/CU
  __shared__ __attribute__((aligned(16))) _Float16 sc[TQ * SC_STRIDE];
  __shared__ __attribute__((aligned(16))) _Float16 vt[DIM * VT_STRIDE];

  const int tid  = threadIdx.x;
  const int w    = tid >> 6;      // wave 0..3
  const int l    = tid & 63;      // lane
  const int n16  = l & 15;
  const int quad = l >> 4;
  const int b    = blockIdx.y;
  const int q0   = blockIdx.x * TQ;

  // ---------------- Phase 1: scores = Q K^T (per-wave column strip, no barriers)
  // A fragments (Q rows q0..q0+15), layout A[m=lane&15][k=quad*8+j]
  const float* qbase = Qg + ((size_t)(b * QLEN + q0 + n16)) * DIM + quad * 8;
  const f16x8 aq0 = cvt_h8(*(const f32x4*)(qbase),      *(const f32x4*)(qbase + 4));
  const f16x8 aq1 = cvt_h8(*(const f32x4*)(qbase + 32), *(const f32x4*)(qbase + 36));

  #pragma unroll 4
  for (int kc = 0; kc < 16; ++kc) {
    const int col = w * 256 + kc * 16 + n16;           // score column == K row
    const float* kbase = Kg + ((size_t)(b * KLEN + col)) * DIM + quad * 8;
    const f16x8 bk0 = cvt_h8(*(const f32x4*)(kbase),      *(const f32x4*)(kbase + 4));
    const f16x8 bk1 = cvt_h8(*(const f32x4*)(kbase + 32), *(const f32x4*)(kbase + 36));
    f32x4 acc = {0.f, 0.f, 0.f, 0.f};
    acc = __builtin_amdgcn_mfma_f32_16x16x32_f16(aq0, bk0, acc, 0, 0, 0);
    acc = __builtin_amdgcn_mfma_f32_16x16x32_f16(aq1, bk1, acc, 0, 0, 0);
    // C layout: row = quad*4 + i, col = lane&15 (store raw dot, f16)
    #pragma unroll
    for (int i = 0; i < 4; ++i)
      sc[(quad * 4 + i) * SC_STRIDE + col] = (_Float16)acc[i];
  }
  __syncthreads();

  // ---------------- Phase 2: scale + mask + softmax; write attn (fp32) + probs (f16, in place)
  for (int rr = 0; rr < 4; ++rr) {
    const int r = w * 4 + rr;
    _Float16* prow = sc + r * SC_STRIDE;
    const int* mrow = Mg + ((size_t)(b * QLEN + q0 + r)) * KLEN;
    float s[16];
    #pragma unroll
    for (int c = 0; c < 4; ++c) {
      const i32x4 mv = *(const i32x4*)(mrow + c * 256 + l * 4);
      const f16x4 hv = *(const f16x4*)(prow + c * 256 + l * 4);
      s[c * 4 + 0] = mv[0] ? -1e9f : (float)hv[0] * 0.125f;
      s[c * 4 + 1] = mv[1] ? -1e9f : (float)hv[1] * 0.125f;
      s[c * 4 + 2] = mv[2] ? -1e9f : (float)hv[2] * 0.125f;
      s[c * 4 + 3] = mv[3] ? -1e9f : (float)hv[3] * 0.125f;
    }
    float mx = s[0];
    #pragma unroll
    for (int j = 1; j < 16; ++j) mx = fmaxf(mx, s[j]);
    #pragma unroll
    for (int d = 1; d < 64; d <<= 1) mx = fmaxf(mx, __shfl_xor(mx, d, 64));
    float sum = 0.f;
    #pragma unroll
    for (int j = 0; j < 16; ++j) { s[j] = __expf(s[j] - mx); sum += s[j]; }
    #pragma unroll
    for (int d = 1; d < 64; d <<= 1) sum += __shfl_xor(sum, d, 64);
    const float inv = 1.0f / sum;
    float* arow = Attn + ((size_t)(b * QLEN + q0 + r)) * KLEN;
    #pragma unroll
    for (int c = 0; c < 4; ++c) {
      f32x4 pv = { s[c*4+0] * inv, s[c*4+1] * inv, s[c*4+2] * inv, s[c*4+3] * inv };
      *(f32x4*)(arow + c * 256 + l * 4) = pv;
      f16x4 hp = { (_Float16)pv[0], (_Float16)pv[1], (_Float16)pv[2], (_Float16)pv[3] };
      *(f16x4*)(prow + c * 256 + l * 4) = hp;
    }
  }
  __syncthreads();

  // ---------------- Phase 3: context = P V  (shared 64x128 V^T tile per chunk)
  f32x4 cacc[4];
  #pragma unroll
  for (int nf = 0; nf < 4; ++nf) cacc[nf] = (f32x4){0.f, 0.f, 0.f, 0.f};

  for (int ch = 0; ch < 8; ++ch) {
    const int kb = ch * 128;
    // stage V[kb..kb+127][0..63] transposed into vt[d][k_local], f16
    #pragma unroll
    for (int s2 = 0; s2 < 2; ++s2) {
      const int dblk = tid & 15;
      const int kblk = (tid >> 4) + 16 * s2;
      const int k4 = kb + kblk * 4, d4 = dblk * 4;
      const float* vbase = Vg + ((size_t)(b * KLEN + k4)) * DIM + d4;
      const f32x4 r0 = *(const f32x4*)(vbase);
      const f32x4 r1 = *(const f32x4*)(vbase + 64);
      const f32x4 r2 = *(const f32x4*)(vbase + 128);
      const f32x4 r3 = *(const f32x4*)(vbase + 192);
      #pragma unroll
      for (int di = 0; di < 4; ++di) {
        f16x4 hw = { (_Float16)r0[di], (_Float16)r1[di], (_Float16)r2[di], (_Float16)r3[di] };
        *(f16x4*)(vt + (d4 + di) * VT_STRIDE + kblk * 4) = hw;
      }
    }
    __syncthreads();
    // wave w consumes k_local = w*32 .. w*32+31 of this chunk (partial sums)
    const f16x8 ap = *(const f16x8*)(sc + n16 * SC_STRIDE + kb + w * 32 + quad * 8);
    #pragma unroll
    for (int nf = 0; nf < 4; ++nf) {
      const f16x8 bv = *(const f16x8*)(vt + (nf * 16 + n16) * VT_STRIDE + w * 32 + quad * 8);
      cacc[nf] = __builtin_amdgcn_mfma_f32_16x16x32_f16(ap, bv, cacc[nf], 0, 0, 0);
    }
    __syncthreads();
  }

  // ---------------- Epilogue: cross-wave reduction of partial contexts
  float* fpart = ((float*)sc) + w * 1024;   // p no longer needed
  #pragma unroll
  for (int nf = 0; nf < 4; ++nf) {
    #pragma unroll
    for (int i = 0; i < 4; ++i)
      fpart[(quad * 4 + i) * 64 + nf * 16 + n16] = cacc[nf][i];
  }
  __syncthreads();
  {
    const float* f0 = (const float*)sc;
    const f32x4 v0 = *(const f32x4*)(f0 + tid * 4);
    const f32x4 v1 = *(const f32x4*)(f0 + 1024 + tid * 4);
    const f32x4 v2 = *(const f32x4*)(f0 + 2048 + tid * 4);
    const f32x4 v3 = *(const f32x4*)(f0 + 3072 + tid * 4);
    const f32x4 s4 = v0 + v1 + v2 + v3;
    *(f32x4*)(Ctx + ((size_t)(b * QLEN + q0)) * DIM + tid * 4) = s4;
  }
}

extern "C" void kernel_launch(void* const* d_in, const int* in_sizes, int n_in,
                              void* d_out, int out_size, void* d_ws, size_t ws_size,
                              hipStream_t stream) {
  const float* Qg = (const float*)d_in[0];
  const float* Kg = (const float*)d_in[1];
  const float* Vg = (const float*)d_in[2];
  const int*   Mg = (const int*)d_in[3];
  float* Ctx  = (float*)d_out;                                     // [32,1024,64]
  float* Attn = (float*)d_out + (size_t)BATCH * QLEN * DIM;        // [32,1024,1024]
  dim3 grid(QLEN / TQ, BATCH);
  sdpa_kernel<<<grid, 256, 0, stream>>>(Qg, Kg, Vg, Mg, Ctx, Attn);
}

// Round 3
// 312.856 us; speedup vs baseline: 1.0049x; 1.0049x over previous
//
#include <hip/hip_runtime.h>

// B=32, Q=K=1024, D=64, fp32 in/out. Outputs: context [B,Q,D] then attn [B,Q,K].
constexpr int BATCH = 32;
constexpr int QLEN  = 1024;
constexpr int KLEN  = 1024;
constexpr int DIM   = 64;
constexpr int TQ    = 16;        // query rows per block
constexpr int SC_STRIDE = 1032;  // f16 elems per score row (1024 + 8 pad)

typedef float    f32x4 __attribute__((ext_vector_type(4)));
typedef int      i32x4 __attribute__((ext_vector_type(4)));
typedef _Float16 f16x8 __attribute__((ext_vector_type(8)));
typedef _Float16 f16x4 __attribute__((ext_vector_type(4)));

__device__ __forceinline__ f16x8 cvt_h8(f32x4 a, f32x4 b) {
  f16x8 h;
  h[0] = (_Float16)a[0]; h[1] = (_Float16)a[1]; h[2] = (_Float16)a[2]; h[3] = (_Float16)a[3];
  h[4] = (_Float16)b[0]; h[5] = (_Float16)b[1]; h[6] = (_Float16)b[2]; h[7] = (_Float16)b[3];
  return h;
}

// ---------------------------------------------------------------- V transpose
// V [B,K,D] f32  ->  Vt [B,D,K] f16   (128 k-rows x 64 d per block)
constexpr int TK = 128;
__global__ __launch_bounds__(256)
void vt_kernel(const float* __restrict__ V, _Float16* __restrict__ Vt) {
  __shared__ _Float16 lt[DIM][TK + 8];
  const int b = blockIdx.y, k0 = blockIdx.x * TK;
  const int t = threadIdx.x;
  const int d4 = (t & 15) * 4;
  #pragma unroll
  for (int p = 0; p < TK / 16; ++p) {
    const int kl = (t >> 4) + p * 16;
    const f32x4 v = *(const f32x4*)(V + ((size_t)(b * KLEN + k0 + kl)) * DIM + d4);
    #pragma unroll
    for (int j = 0; j < 4; ++j) lt[d4 + j][kl] = (_Float16)v[j];
  }
  __syncthreads();
  // 64 d-rows x 16 f16x8-segments = 1024 stores over 256 threads -> 4 each.
  const int d = t >> 2;
  #pragma unroll
  for (int j2 = 0; j2 < TK / 32; ++j2) {   // 4 iterations (was TK/64 = 2: BUG, half of Vt unwritten)
    const int seg = (t & 3) + j2 * 4;      // 0..15
    *(f16x8*)(Vt + (size_t)b * DIM * KLEN + (size_t)d * KLEN + k0 + seg * 8) =
        *(const f16x8*)(&lt[d][seg * 8]);
  }
}

// ---------------------------------------------------------------- fused SDPA
__global__ __launch_bounds__(256, 4)
void sdpa_kernel(const float* __restrict__ Qg, const float* __restrict__ Kg,
                 const _Float16* __restrict__ Vt, const int* __restrict__ Mg,
                 float* __restrict__ Ctx, float* __restrict__ Attn)
{
  __shared__ __attribute__((aligned(16))) _Float16 sc[TQ * SC_STRIDE]; // 33,024 B -> 4 blocks/CU

  const int tid  = threadIdx.x;
  const int w    = tid >> 6;
  const int l    = tid & 63;
  const int n16  = l & 15;
  const int quad = l >> 4;
  const int b    = blockIdx.y;
  const int q0   = blockIdx.x * TQ;

  // Prefetch mask for this wave's first two softmax rows (hidden under phase 1).
  const int* mrow0 = Mg + ((size_t)(b * QLEN + q0 + w * 4)) * KLEN;
  i32x4 mva[2][4];
  #pragma unroll
  for (int j = 0; j < 2; ++j)
    #pragma unroll
    for (int c = 0; c < 4; ++c)
      mva[j][c] = *(const i32x4*)(mrow0 + j * KLEN + c * 256 + l * 4);

  // ---------------- Phase 1: raw scores = Q K^T  (per-wave 256-col strip)
  const float* qbase = Qg + ((size_t)(b * QLEN + q0 + n16)) * DIM + quad * 8;
  const f16x8 aq0 = cvt_h8(*(const f32x4*)(qbase),      *(const f32x4*)(qbase + 4));
  const f16x8 aq1 = cvt_h8(*(const f32x4*)(qbase + 32), *(const f32x4*)(qbase + 36));

  #pragma unroll 4
  for (int kc = 0; kc < 16; ++kc) {
    const int col = w * 256 + kc * 16 + n16;
    const float* kbase = Kg + ((size_t)(b * KLEN + col)) * DIM + quad * 8;
    const f16x8 bk0 = cvt_h8(*(const f32x4*)(kbase),      *(const f32x4*)(kbase + 4));
    const f16x8 bk1 = cvt_h8(*(const f32x4*)(kbase + 32), *(const f32x4*)(kbase + 36));
    f32x4 acc = {0.f, 0.f, 0.f, 0.f};
    acc = __builtin_amdgcn_mfma_f32_16x16x32_f16(aq0, bk0, acc, 0, 0, 0);
    acc = __builtin_amdgcn_mfma_f32_16x16x32_f16(aq1, bk1, acc, 0, 0, 0);
    #pragma unroll
    for (int i = 0; i < 4; ++i)
      sc[(quad * 4 + i) * SC_STRIDE + col] = (_Float16)acc[i];
  }
  __syncthreads();

  // ---------------- Phase 2: scale+mask+softmax; attn fp32 out, probs f16 in place
  #pragma unroll
  for (int pp = 0; pp < 2; ++pp) {
    i32x4 mv[2][4];
    if (pp == 0) {
      #pragma unroll
      for (int j = 0; j < 2; ++j)
        #pragma unroll
        for (int c = 0; c < 4; ++c) mv[j][c] = mva[j][c];
    } else {
      #pragma unroll
      for (int j = 0; j < 2; ++j)
        #pragma unroll
        for (int c = 0; c < 4; ++c)
          mv[j][c] = *(const i32x4*)(mrow0 + (2 + j) * KLEN + c * 256 + l * 4);
    }
    #pragma unroll
    for (int j = 0; j < 2; ++j) {
      const int r = w * 4 + pp * 2 + j;
      _Float16* prow = sc + r * SC_STRIDE;
      float s[16];
      #pragma unroll
      for (int c = 0; c < 4; ++c) {
        const f16x4 hv = *(const f16x4*)(prow + c * 256 + l * 4);
        s[c * 4 + 0] = mv[j][c][0] ? -1e9f : (float)hv[0] * 0.125f;
        s[c * 4 + 1] = mv[j][c][1] ? -1e9f : (float)hv[1] * 0.125f;
        s[c * 4 + 2] = mv[j][c][2] ? -1e9f : (float)hv[2] * 0.125f;
        s[c * 4 + 3] = mv[j][c][3] ? -1e9f : (float)hv[3] * 0.125f;
      }
      float mx = s[0];
      #pragma unroll
      for (int jj = 1; jj < 16; ++jj) mx = fmaxf(mx, s[jj]);
      #pragma unroll
      for (int d = 1; d < 64; d <<= 1) mx = fmaxf(mx, __shfl_xor(mx, d, 64));
      float sum = 0.f;
      #pragma unroll
      for (int jj = 0; jj < 16; ++jj) { s[jj] = __expf(s[jj] - mx); sum += s[jj]; }
      #pragma unroll
      for (int d = 1; d < 64; d <<= 1) sum += __shfl_xor(sum, d, 64);
      const float inv = 1.0f / sum;
      float* arow = Attn + ((size_t)(b * QLEN + q0 + r)) * KLEN;
      #pragma unroll
      for (int c = 0; c < 4; ++c) {
        f32x4 pv = { s[c*4+0] * inv, s[c*4+1] * inv, s[c*4+2] * inv, s[c*4+3] * inv };
        *(f32x4*)(arow + c * 256 + l * 4) = pv;
        f16x4 hp = { (_Float16)pv[0], (_Float16)pv[1], (_Float16)pv[2], (_Float16)pv[3] };
        *(f16x4*)(prow + c * 256 + l * 4) = hp;
      }
    }
  }
  __syncthreads();

  // ---------------- Phase 3: context = P V. Wave w owns output-column tile w
  // (cols w*16+n16) over the FULL K range. B-fragments straight from global Vt
  // (L2-resident). No barriers, no cross-wave reduction.
  const _Float16* vtb = Vt + (size_t)b * DIM * KLEN + (size_t)(w * 16 + n16) * KLEN;
  const _Float16* prow = sc + n16 * SC_STRIDE;
  f32x4 cacc = {0.f, 0.f, 0.f, 0.f};
  #pragma unroll 4
  for (int kk = 0; kk < 32; ++kk) {
    const f16x8 ap = *(const f16x8*)(prow + kk * 32 + quad * 8);
    const f16x8 bv = *(const f16x8*)(vtb + kk * 32 + quad * 8);
    cacc = __builtin_amdgcn_mfma_f32_16x16x32_f16(ap, bv, cacc, 0, 0, 0);
  }
  float* cbase = Ctx + ((size_t)(b * QLEN + q0 + quad * 4)) * DIM + w * 16 + n16;
  #pragma unroll
  for (int i = 0; i < 4; ++i) cbase[(size_t)i * DIM] = cacc[i];
}

extern "C" void kernel_launch(void* const* d_in, const int* in_sizes, int n_in,
                              void* d_out, int out_size, void* d_ws, size_t ws_size,
                              hipStream_t stream) {
  const float* Qg = (const float*)d_in[0];
  const float* Kg = (const float*)d_in[1];
  const float* Vg = (const float*)d_in[2];
  const int*   Mg = (const int*)d_in[3];
  float* Ctx  = (float*)d_out;                                  // [32,1024,64]
  float* Attn = (float*)d_out + (size_t)BATCH * QLEN * DIM;     // [32,1024,1024]
  _Float16* Vt = (_Float16*)d_ws;                               // [32,64,1024] f16, 4 MB

  dim3 tgrid(KLEN / TK, BATCH);
  vt_kernel<<<tgrid, 256, 0, stream>>>(Vg, Vt);

  dim3 grid(QLEN / TQ, BATCH);
  sdpa_kernel<<<grid, 256, 0, stream>>>(Qg, Kg, Vt, Mg, Ctx, Attn);
}